// Round 5
// baseline (4121.596 us; speedup 1.0000x reference)
//
#include <hip/hip_runtime.h>

typedef __attribute__((ext_vector_type(8))) short short8;
typedef __attribute__((ext_vector_type(4))) float f32x4;
typedef __attribute__((ext_vector_type(4))) unsigned int u32x4;

#define T_   512
#define B_   64
#define I_   256
#define H_   512
#define BH   (B_*H_)   // 32768
#define NB0  32
#define R_   64        // hs ring slots

// ---- ws layout (bytes) ----
#define WS_XB   0u            // bf16 X [512][64][256]            16,777,216
#define WS_HSU  16777216u     // u32 tagged hs ring [64][64][512]  8,388,608
#define WS_H1U  25165824u     // u32 tagged h1 ring [2][64][512]     262,144
#define WS_P0   25427968u     // packed W0cat                      3,145,728
#define WS_P1   28573696u     // packed W1cat                      4,194,304
#define WS_B0   32768000u     // f32 bias0 [2048]
#define WS_B1   32776192u     // f32 bias1 [2048]
#define WS_PRG  32784384u     // 128 u32 progress flags, 64B apart (8 KB)

__device__ __forceinline__ unsigned short f2b(float f) {
    unsigned int x = __builtin_bit_cast(unsigned int, f);
    unsigned int r = (x + 0x7fffu + ((x >> 16) & 1u)) >> 16;   // RNE
    return (unsigned short)r;
}

// ---- coherent (cross-XCD, MALL) primitives ----
template<int OFF>
__device__ __forceinline__ u32x4 ldcu4(const unsigned* p) {
    u32x4 r;
    asm volatile("global_load_dwordx4 %0, %1, off offset:%c2 sc0 sc1"
                 : "=v"(r) : "v"(p), "i"(OFF));
    return r;
}
__device__ __forceinline__ void stcu4(unsigned* p, u32x4 v) {
    asm volatile("global_store_dwordx4 %0, %1, off sc0 sc1" :: "v"(p), "v"(v) : "memory");
}
__device__ __forceinline__ void stc32(unsigned* p, unsigned v) {
    asm volatile("global_store_dword %0, %1, off sc0 sc1" :: "v"(p), "v"(v) : "memory");
}
__device__ __forceinline__ unsigned ldc32(const unsigned* p) {
    unsigned v;
    asm volatile("global_load_dword %0, %1, off sc0 sc1\n\ts_waitcnt vmcnt(0)"
                 : "=v"(v) : "v"(p) : "memory");
    return v;
}
#define SWAIT(N) do { asm volatile("s_waitcnt vmcnt(" #N ")" ::: "memory"); \
                      __builtin_amdgcn_sched_barrier(0); } while (0)

// chunk = 4 k-steps = 8 u32x4 per lane (k = ks*32 + lk*8 + e, this lane's 8 u32 per ks)
__device__ __forceinline__ void issue_chunk(const unsigned* p, u32x4 v[8]) {
    v[0] = ldcu4<0>(p);   v[1] = ldcu4<16>(p);
    v[2] = ldcu4<128>(p); v[3] = ldcu4<144>(p);
    v[4] = ldcu4<256>(p); v[5] = ldcu4<272>(p);
    v[6] = ldcu4<384>(p); v[7] = ldcu4<400>(p);
}
__device__ __forceinline__ bool chunk_ok(const u32x4 v[8], unsigned tag) {
    unsigned m = 0;
#pragma unroll
    for (int i = 0; i < 8; i++) {
        m |= (v[i][0] ^ tag); m |= (v[i][1] ^ tag);
        m |= (v[i][2] ^ tag); m |= (v[i][3] ^ tag);
    }
    return (m & 0xffffu) == 0;
}
__device__ __forceinline__ void validate_retry(u32x4 v[8], const unsigned* p, unsigned tag) {
    while (!__all(chunk_ok(v, tag))) {
        issue_chunk(p, v);
        SWAIT(0);
    }
}
__device__ __forceinline__ short8 pack_frag(const u32x4& a, const u32x4& b) {
    u32x4 r;
    r[0] = (a[0] >> 16) | (a[1] & 0xffff0000u);
    r[1] = (a[2] >> 16) | (a[3] & 0xffff0000u);
    r[2] = (b[0] >> 16) | (b[1] & 0xffff0000u);
    r[3] = (b[2] >> 16) | (b[3] & 0xffff0000u);
    return __builtin_bit_cast(short8, r);
}

// X f32 -> bf16, and copy inputs to output tail (outputs: h_n|c_n|inputs)
__global__ void convert_x(const float* __restrict__ X, unsigned short* __restrict__ Xb,
                          float* __restrict__ outcpy) {
    const int n4 = (T_ * B_ * I_) / 4;
    for (int i = blockIdx.x * blockDim.x + threadIdx.x; i < n4; i += gridDim.x * blockDim.x) {
        float4 v = reinterpret_cast<const float4*>(X)[i];
        ushort4 u;
        u.x = f2b(v.x); u.y = f2b(v.y); u.z = f2b(v.z); u.w = f2b(v.w);
        reinterpret_cast<ushort4*>(Xb)[i] = u;
        reinterpret_cast<float4*>(outcpy)[i] = v;
    }
}

// Pack Wcat0 = [Wih0 | Whh0] (K=768) into 16x16x32 B-fragment order.
__global__ void pack_w0(const float* __restrict__ Wih, const float* __restrict__ Whh,
                        unsigned short* __restrict__ p0) {
    const int n = 32 * 4 * 24 * 64;
    int idx = blockIdx.x * blockDim.x + threadIdx.x;
    if (idx >= n) return;
    int lane = idx & 63; int q = idx >> 6;
    int ks = q % 24; q /= 24;
    int g = q & 3;   int j = q >> 2;
    int row_w = g * 512 + j * 16 + (lane & 15);
    int k0 = ks * 32 + (lane >> 4) * 8;
    short8 o;
#pragma unroll
    for (int e = 0; e < 8; e++) {
        int k = k0 + e;
        float v = (k < 256) ? Wih[row_w * 256 + k] : Whh[row_w * 512 + (k - 256)];
        o[e] = (short)f2b(v);
    }
    reinterpret_cast<short8*>(p0)[idx] = o;
}

// Wcat1 = [Wih1 | Whh1] (K=1024), 32 k-steps
__global__ void pack_w1(const float* __restrict__ Wih, const float* __restrict__ Whh,
                        unsigned short* __restrict__ p1) {
    const int n = 32 * 4 * 32 * 64;
    int idx = blockIdx.x * blockDim.x + threadIdx.x;
    if (idx >= n) return;
    int lane = idx & 63; int q = idx >> 6;
    int ks = q & 31; q >>= 5;
    int g = q & 3;   int j = q >> 2;
    int row_w = g * 512 + j * 16 + (lane & 15);
    int k0 = ks * 32 + (lane >> 4) * 8;
    short8 o;
#pragma unroll
    for (int e = 0; e < 8; e++) {
        int k = k0 + e;
        float v = (k < 512) ? Wih[row_w * 512 + k] : Whh[row_w * 512 + (k - 512)];
        o[e] = (short)f2b(v);
    }
    reinterpret_cast<short8*>(p1)[idx] = o;
}

// biases + tagged initial states + progress flags
__global__ void prep_misc(const float* __restrict__ bih0, const float* __restrict__ bhh0,
                          const float* __restrict__ bih1, const float* __restrict__ bhh1,
                          const float* __restrict__ h0,
                          float* __restrict__ b0c, float* __restrict__ b1c,
                          unsigned* __restrict__ hsu, unsigned* __restrict__ h1u,
                          unsigned* __restrict__ prg) {
    int i = blockIdx.x * blockDim.x + threadIdx.x;
    if (i < 2048) b0c[i] = bih0[i] + bhh0[i];
    else if (i < 4096) { int k = i - 2048; b1c[k] = bih1[k] + bhh1[k]; }
    else if (i < 4096 + BH) { int k = i - 4096; hsu[k] = ((unsigned)f2b(h0[k]) << 16); }          // slot0, tag0
    else if (i < 4096 + 2 * BH) { int k = i - 4096 - BH; h1u[k] = ((unsigned)f2b(h0[BH + k]) << 16); }
    else if (i < 4096 + 2 * BH + 2048) { prg[i - 4096 - 2 * BH] = 0u; }
}

// Persistent dataflow LSTM: 64 blocks x 256 threads, NO barriers/flags on critical path.
// Blocks 0..31: layer 0 (block j owns h-cols j*16..+15). Blocks 32..63: layer 1.
// All cross-block h traffic is tagged u32 (bf16<<16 | step), spin-validated at the consumer.
__global__ void __launch_bounds__(256, 1) lstm_pers(
    const unsigned short* __restrict__ Xb,
    unsigned* __restrict__ hsu,
    unsigned* __restrict__ h1u,
    const unsigned short* __restrict__ p0,
    const unsigned short* __restrict__ p1,
    const float* __restrict__ b0c,
    const float* __restrict__ b1c,
    const float* __restrict__ c0,
    float* __restrict__ out,
    unsigned* __restrict__ prg) {
    __shared__ __align__(16) unsigned char smem[135168];   // 128KB weights + 4KB transpose
    unsigned short* bsh = (unsigned short*)smem;

    const int bid = blockIdx.x;
    const int tid = threadIdx.x;
    const int lane = tid & 63;
    const int w = tid >> 6;
    const int la = lane & 15;      // A-row / D-col within tile
    const int lk = lane >> 4;      // k-subgroup; D-rows = lk*4+reg
    const int hc = la;
    unsigned* tr = (unsigned*)(smem + 131072) + w * 256;   // per-wave 16x16 u32 tile

    // wave-local transpose + coalesced tagged store of this wave's 16x16 tile
    auto store_tile = [&](unsigned* dst_base, const float h[4], unsigned tag) {
#pragma unroll
        for (int r = 0; r < 4; r++)
            tr[(lk * 4 + r) * 16 + la] = ((unsigned)f2b(h[r]) << 16) | tag;
        asm volatile("s_waitcnt lgkmcnt(0)" ::: "memory");
        __builtin_amdgcn_sched_barrier(0);
        int row = lane >> 2, c4 = (lane & 3) * 4;
        u32x4 v = *reinterpret_cast<const u32x4*>(tr + row * 16 + c4);
        stcu4(dst_base + row * 512 + c4, v);
    };

    if (bid < NB0) {
        // ================= layer 0 =================
        const int j = bid;
        {
            const short8* src = reinterpret_cast<const short8*>(p0 + (size_t)j * 49152);
            short8* dst = reinterpret_cast<short8*>(bsh);
            for (int i = tid; i < 6144; i += 256) dst[i] = src[i];
        }
        __syncthreads();

        const float bi = b0c[       j * 16 + hc];
        const float bf = b0c[512  + j * 16 + hc];
        const float bg = b0c[1024 + j * 16 + hc];
        const float bo = b0c[1536 + j * 16 + hc];
        float c[4];
#pragma unroll
        for (int r = 0; r < 4; r++) c[r] = c0[(w * 16 + lk * 4 + r) * 512 + j * 16 + hc];

        // x-part for step 0
        f32x4 a0 = {0.f,0.f,0.f,0.f}, a1 = a0, a2 = a0, a3 = a0;
        {
            const unsigned short* xr = Xb + (size_t)(w * 16 + la) * 256 + lk * 8;
#pragma unroll
            for (int ks = 0; ks < 8; ks++) {
                short8 av = *reinterpret_cast<const short8*>(xr + ks * 32);
                const unsigned short* bb = bsh + ks * 512 + lane * 8;
                a0 = __builtin_amdgcn_mfma_f32_16x16x32_bf16(av, *reinterpret_cast<const short8*>(bb        ), a0, 0, 0, 0);
                a1 = __builtin_amdgcn_mfma_f32_16x16x32_bf16(av, *reinterpret_cast<const short8*>(bb + 12288), a1, 0, 0, 0);
                a2 = __builtin_amdgcn_mfma_f32_16x16x32_bf16(av, *reinterpret_cast<const short8*>(bb + 24576), a2, 0, 0, 0);
                a3 = __builtin_amdgcn_mfma_f32_16x16x32_bf16(av, *reinterpret_cast<const short8*>(bb + 36864), a3, 0, 0, 0);
            }
        }

        for (int n = 0; n < T_; n++) {
            // ring backpressure vs layer-1 consumption (off critical path, rare)
            if (n >= R_ && (n & 15) == 0) {
                const unsigned thr = (unsigned)(n - 48);
                for (;;) {
                    unsigned v1 = ldc32(prg + lane * 16);
                    unsigned v2 = ldc32(prg + (lane + 64) * 16);
                    if (__all(v1 >= thr && v2 >= thr)) break;
                }
            }
            // h-part: K=512 over tagged h[n] (slot n&63, tag n), chunked + double-buffered
            const unsigned* hp = hsu + (size_t)(n & (R_ - 1)) * BH + (size_t)(w * 16 + la) * 512 + lk * 8;
            u32x4 va[8], vb[8];
            issue_chunk(hp, va);
#pragma unroll
            for (int cch = 0; cch < 4; cch++) {
                u32x4* cur = (cch & 1) ? vb : va;
                u32x4* nxt = (cch & 1) ? va : vb;
                if (cch < 3) { issue_chunk(hp + (cch + 1) * 128, nxt); SWAIT(8); }
                else         { SWAIT(0); }
                validate_retry(cur, hp + cch * 128, (unsigned)n);
#pragma unroll
                for (int kk = 0; kk < 4; kk++) {
                    short8 af = pack_frag(cur[2 * kk], cur[2 * kk + 1]);
                    const unsigned short* bb = bsh + (8 + 4 * cch + kk) * 512 + lane * 8;
                    a0 = __builtin_amdgcn_mfma_f32_16x16x32_bf16(af, *reinterpret_cast<const short8*>(bb        ), a0, 0, 0, 0);
                    a1 = __builtin_amdgcn_mfma_f32_16x16x32_bf16(af, *reinterpret_cast<const short8*>(bb + 12288), a1, 0, 0, 0);
                    a2 = __builtin_amdgcn_mfma_f32_16x16x32_bf16(af, *reinterpret_cast<const short8*>(bb + 24576), a2, 0, 0, 0);
                    a3 = __builtin_amdgcn_mfma_f32_16x16x32_bf16(af, *reinterpret_cast<const short8*>(bb + 36864), a3, 0, 0, 0);
                }
            }
            float h[4];
#pragma unroll
            for (int r = 0; r < 4; r++) {
                float ip = a0[r] + bi, fp = a1[r] + bf, gp = a2[r] + bg, op = a3[r] + bo;
                float si = 1.f / (1.f + __expf(-ip));
                float sf = 1.f / (1.f + __expf(-fp));
                float so = 1.f / (1.f + __expf(-op));
                float tg = tanhf(gp);
                float cn = sf * c[r] + si * tg;
                h[r] = so * tanhf(cn);
                c[r] = cn;
                if (n == T_ - 1) {
                    int row = w * 16 + lk * 4 + r;
                    out[row * 512 + j * 16 + hc] = h[r];          // h_n[0]
                    out[65536 + row * 512 + j * 16 + hc] = cn;    // c_n[0]
                }
            }
            store_tile(hsu + (size_t)((n + 1) & (R_ - 1)) * BH + (size_t)(w * 16) * 512 + j * 16,
                       h, (unsigned)(n + 1));
            if (n < T_ - 1) {   // x-part for step n+1, off critical path (hides store latency)
                f32x4 z = {0.f,0.f,0.f,0.f};
                a0 = z; a1 = z; a2 = z; a3 = z;
                const unsigned short* xr = Xb + ((size_t)(n + 1) * B_ + w * 16 + la) * 256 + lk * 8;
#pragma unroll
                for (int ks = 0; ks < 8; ks++) {
                    short8 av = *reinterpret_cast<const short8*>(xr + ks * 32);
                    const unsigned short* bb = bsh + ks * 512 + lane * 8;
                    a0 = __builtin_amdgcn_mfma_f32_16x16x32_bf16(av, *reinterpret_cast<const short8*>(bb        ), a0, 0, 0, 0);
                    a1 = __builtin_amdgcn_mfma_f32_16x16x32_bf16(av, *reinterpret_cast<const short8*>(bb + 12288), a1, 0, 0, 0);
                    a2 = __builtin_amdgcn_mfma_f32_16x16x32_bf16(av, *reinterpret_cast<const short8*>(bb + 24576), a2, 0, 0, 0);
                    a3 = __builtin_amdgcn_mfma_f32_16x16x32_bf16(av, *reinterpret_cast<const short8*>(bb + 36864), a3, 0, 0, 0);
                }
            }
        }
    } else {
        // ================= layer 1 =================
        const int j = bid - NB0;
        {
            const short8* src = reinterpret_cast<const short8*>(p1 + (size_t)j * 65536);
            short8* dst = reinterpret_cast<short8*>(bsh);
            for (int i = tid; i < 8192; i += 256) dst[i] = src[i];
        }
        __syncthreads();

        const float bi = b1c[       j * 16 + hc];
        const float bf = b1c[512  + j * 16 + hc];
        const float bg = b1c[1024 + j * 16 + hc];
        const float bo = b1c[1536 + j * 16 + hc];
        float c[4];
#pragma unroll
        for (int r = 0; r < 4; r++) c[r] = c0[BH + (w * 16 + lk * 4 + r) * 512 + j * 16 + hc];

        for (int s = 0; s < T_; s++) {
            const unsigned* base0 = hsu + (size_t)((s + 1) & (R_ - 1)) * BH + (size_t)(w * 16 + la) * 512 + lk * 8;
            const unsigned* base1 = h1u + (size_t)(s & 1) * BH + (size_t)(w * 16 + la) * 512 + lk * 8;
            const unsigned tag0 = (unsigned)(s + 1), tag1 = (unsigned)s;
            f32x4 z = {0.f,0.f,0.f,0.f};
            f32x4 a0 = z, a1 = z, a2 = z, a3 = z;
            u32x4 va[8], vb[8];
            issue_chunk(base0, va);
#pragma unroll
            for (int cch = 0; cch < 8; cch++) {
                u32x4* cur = (cch & 1) ? vb : va;
                u32x4* nxt = (cch & 1) ? va : vb;
                const unsigned* curp = (cch < 4) ? base0 + cch * 128 : base1 + (cch - 4) * 128;
                if (cch < 7) {
                    const unsigned* nxtp = (cch < 3) ? base0 + (cch + 1) * 128 : base1 + (cch - 3) * 128;
                    issue_chunk(nxtp, nxt); SWAIT(8);
                } else SWAIT(0);
                validate_retry(cur, curp, (cch < 4) ? tag0 : tag1);
#pragma unroll
                for (int kk = 0; kk < 4; kk++) {
                    short8 af = pack_frag(cur[2 * kk], cur[2 * kk + 1]);
                    const unsigned short* bb = bsh + (4 * cch + kk) * 512 + lane * 8;
                    a0 = __builtin_amdgcn_mfma_f32_16x16x32_bf16(af, *reinterpret_cast<const short8*>(bb        ), a0, 0, 0, 0);
                    a1 = __builtin_amdgcn_mfma_f32_16x16x32_bf16(af, *reinterpret_cast<const short8*>(bb + 16384), a1, 0, 0, 0);
                    a2 = __builtin_amdgcn_mfma_f32_16x16x32_bf16(af, *reinterpret_cast<const short8*>(bb + 32768), a2, 0, 0, 0);
                    a3 = __builtin_amdgcn_mfma_f32_16x16x32_bf16(af, *reinterpret_cast<const short8*>(bb + 49152), a3, 0, 0, 0);
                }
            }
            float h[4];
#pragma unroll
            for (int r = 0; r < 4; r++) {
                float ip = a0[r] + bi, fp = a1[r] + bf, gp = a2[r] + bg, op = a3[r] + bo;
                float si = 1.f / (1.f + __expf(-ip));
                float sf = 1.f / (1.f + __expf(-fp));
                float so = 1.f / (1.f + __expf(-op));
                float tg = tanhf(gp);
                float cn = sf * c[r] + si * tg;
                h[r] = so * tanhf(cn);
                c[r] = cn;
                if (s == T_ - 1) {
                    int row = w * 16 + lk * 4 + r;
                    out[BH + row * 512 + j * 16 + hc] = h[r];            // h_n[1]
                    out[65536 + BH + row * 512 + j * 16 + hc] = cn;      // c_n[1]
                }
            }
            if (s < T_ - 1)
                store_tile(h1u + (size_t)((s + 1) & 1) * BH + (size_t)(w * 16) * 512 + j * 16,
                           h, (unsigned)(s + 1));
            // per-wave progress flag (ring backpressure for layer 0); monotone, no drain needed
            if (lane == 0) stc32(prg + (j * 4 + w) * 16, (unsigned)s);
        }
    }
}

extern "C" void kernel_launch(void* const* d_in, const int* in_sizes, int n_in,
                              void* d_out, int out_size, void* d_ws, size_t ws_size,
                              hipStream_t stream) {
    const float* X    = (const float*)d_in[0];
    const float* h0   = (const float*)d_in[1];
    const float* c0   = (const float*)d_in[2];
    const float* wih0 = (const float*)d_in[3];
    const float* whh0 = (const float*)d_in[4];
    const float* bih0 = (const float*)d_in[5];
    const float* bhh0 = (const float*)d_in[6];
    const float* wih1 = (const float*)d_in[7];
    const float* whh1 = (const float*)d_in[8];
    const float* bih1 = (const float*)d_in[9];
    const float* bhh1 = (const float*)d_in[10];
    float* out = (float*)d_out;
    char* ws = (char*)d_ws;

    unsigned short* Xb = (unsigned short*)(ws + WS_XB);
    unsigned* hsu = (unsigned*)(ws + WS_HSU);
    unsigned* h1u = (unsigned*)(ws + WS_H1U);
    unsigned short* p0 = (unsigned short*)(ws + WS_P0);
    unsigned short* p1 = (unsigned short*)(ws + WS_P1);
    float* b0c = (float*)(ws + WS_B0);
    float* b1c = (float*)(ws + WS_B1);
    unsigned* prg = (unsigned*)(ws + WS_PRG);

    hipLaunchKernelGGL(convert_x, dim3(2048), dim3(256), 0, stream, X, Xb, out + 131072);
    hipLaunchKernelGGL(pack_w0, dim3(768), dim3(256), 0, stream, wih0, whh0, p0);
    hipLaunchKernelGGL(pack_w1, dim3(1024), dim3(256), 0, stream, wih1, whh1, p1);
    hipLaunchKernelGGL(prep_misc, dim3(512), dim3(256), 0, stream,
                       bih0, bhh0, bih1, bhh1, h0, b0c, b1c, hsu, h1u, prg);
    hipLaunchKernelGGL(lstm_pers, dim3(64), dim3(256), 0, stream,
                       Xb, hsu, h1u, p0, p1, b0c, b1c, c0, out, prg);
}